// Round 9
// baseline (448.241 us; speedup 1.0000x reference)
//
#include <hip/hip_runtime.h>

#define N_NODES 100000
#define N_EDGES 400000
#define D 128
#define BN_EPS 1e-5f
#define NTILES 6250   // N_NODES/16

typedef short short8 __attribute__((ext_vector_type(8)));   // 8 bf16 as raw shorts (4 VGPRs)
typedef float f32x4 __attribute__((ext_vector_type(4)));

static __device__ __forceinline__ float bf2f(unsigned short u) {
    unsigned x = ((unsigned)u) << 16;
    return __builtin_bit_cast(float, x);
}
static __device__ __forceinline__ unsigned short f2bf(float f) {
    unsigned x = __builtin_bit_cast(unsigned, f);
    x += 0x7fffu + ((x >> 16) & 1u);   // round-to-nearest-even
    return (unsigned short)(x >> 16);
}
// split f32 into bf16 hi + bf16 lo (a ~= hi + lo, residual ~2^-17 rel)
static __device__ __forceinline__ void splitbf(float a, short& hi, short& lo) {
    unsigned short h = f2bf(a);
    float r = a - bf2f(h);
    hi = (short)h;
    lo = (short)f2bf(r);
}

// ---------------------------------------------------------------- fallback: clean zero-fill of d_out
__global__ void k_zero_out(float* __restrict__ y, int n4) {
    int t = blockIdx.x * blockDim.x + threadIdx.x;
    if (t < n4) ((float4*)y)[t] = float4{0.f, 0.f, 0.f, 0.f};
}

// ---------------------------------------------------------------- degree histograms
__global__ void k_count(const int* __restrict__ src, const int* __restrict__ dst,
                        int* __restrict__ cnt_src, int* __restrict__ cnt_dst) {
    int t = blockIdx.x * blockDim.x + threadIdx.x;
    if (t >= N_EDGES) return;
    atomicAdd(&cnt_src[src[t]], 1);
    atomicAdd(&cnt_dst[dst[t]], 1);
}

// ---------------------------------------------------------------- rsqrt coeffs (+ zero the fill cursors)
__global__ void k_coeffs(const int* __restrict__ cnt_src, const int* __restrict__ cnt_dst,
                         float* __restrict__ c_src, float* __restrict__ c_dst,
                         int* __restrict__ fill) {
    int t = blockIdx.x * blockDim.x + threadIdx.x;
    if (t >= N_NODES) return;
    c_src[t] = rsqrtf(fmaxf((float)cnt_src[t], 1.0f));
    c_dst[t] = rsqrtf(fmaxf((float)cnt_dst[t], 1.0f));
    fill[t] = 0;
}

// ---------------------------------------------------------------- exclusive scan, level 1 (256/block)
__global__ void k_scan1(const int* __restrict__ cnt, int* __restrict__ outp,
                        int* __restrict__ bsum) {
    __shared__ int s[256];
    int i = blockIdx.x * 256 + threadIdx.x;
    int v = (i < N_NODES) ? cnt[i] : 0;
    s[threadIdx.x] = v;
    __syncthreads();
    for (int d = 1; d < 256; d <<= 1) {
        int t = (threadIdx.x >= d) ? s[threadIdx.x - d] : 0;
        __syncthreads();
        s[threadIdx.x] += t;
        __syncthreads();
    }
    if (i < N_NODES) outp[i] = s[threadIdx.x] - v;   // exclusive
    if (threadIdx.x == 255) bsum[blockIdx.x] = s[255];
}

// ---------------------------------------------------------------- exclusive scan, level 2 (single block, nb<=512)
__global__ void k_scan2(int* __restrict__ bsum, int nb) {
    __shared__ int s[512];
    int v = (threadIdx.x < nb) ? bsum[threadIdx.x] : 0;
    s[threadIdx.x] = v;
    __syncthreads();
    for (int d = 1; d < 512; d <<= 1) {
        int t = (threadIdx.x >= d) ? s[threadIdx.x - d] : 0;
        __syncthreads();
        s[threadIdx.x] += t;
        __syncthreads();
    }
    if (threadIdx.x < nb) bsum[threadIdx.x] = s[threadIdx.x] - v;
}

// ---------------------------------------------------------------- scan fixup
__global__ void k_scan3(int* __restrict__ rowStart, const int* __restrict__ boff) {
    int i = blockIdx.x * 256 + threadIdx.x;
    if (i < N_NODES) rowStart[i] += boff[i >> 8];
    if (i == 0) rowStart[N_NODES] = N_EDGES;
}

// ---------------------------------------------------------------- bucket-fill: edge srcs sorted by dst
__global__ void k_fill(const int* __restrict__ src, const int* __restrict__ dst,
                       const int* __restrict__ rowStart, int* __restrict__ fill,
                       int* __restrict__ esorted) {
    int e = blockIdx.x * blockDim.x + threadIdx.x;
    if (e >= N_EDGES) return;
    int d = dst[e];
    int pos = rowStart[d] + atomicAdd(&fill[d], 1);
    esorted[pos] = src[e];
}

// ---------------------------------------------------------------- W(f32) -> MFMA B-fragment order, split hi/lo bf16
// frag layout: fragIdx = ntile*4 + kstep; element j of lane l = W[kstep*32 + (l>>4)*8 + j][ntile*16 + (l&15)]
__global__ void k_make_frags(const float* __restrict__ W,
                             const float* __restrict__ Wr,
                             unsigned short* __restrict__ Whi, unsigned short* __restrict__ Wlo,
                             unsigned short* __restrict__ Wrhi, unsigned short* __restrict__ Wrlo) {
    int t = blockIdx.x * blockDim.x + threadIdx.x;   // 0..4095
    if (t >= 4096) return;
    int mat = t >> 11;
    int fragIdx = (t >> 6) & 31;
    int lane = t & 63;
    int nt = fragIdx >> 2, ks = fragIdx & 3;
    const float* Wsrc = mat ? Wr : W;
    unsigned short* dhi = mat ? Wrhi : Whi;
    unsigned short* dlo = mat ? Wrlo : Wlo;
    int n = nt * 16 + (lane & 15);
    int kbase = ks * 32 + (lane >> 4) * 8;
    short hi[8], lo[8];
#pragma unroll
    for (int j = 0; j < 8; j++) splitbf(Wsrc[(kbase + j) * D + n], hi[j], lo[j]);
    ((uint4*)dhi)[fragIdx * 64 + lane] = *(uint4*)hi;
    ((uint4*)dlo)[fragIdx * 64 + lane] = *(uint4*)lo;
}

// ---------------------------------------------------------------- fused gather + dual GEMM, weights-in-VGPR
// Per 16-row tile: phase A gathers agg rows from sorted edges into LDS (f32, c_dst applied);
// phase B builds split-bf16 frags (agg from LDS, x from global) and runs MFMA.
// block = 4 waves; wave w owns cols [w*32, w*32+32). y staged in LDS, full 512B row stores.
__global__ __launch_bounds__(256, 2) void k_gemm_fused(
    const float* __restrict__ x,               // [N,128] f32
    const int* __restrict__ esorted, const int* __restrict__ rowStart,
    const float* __restrict__ c_src, const float* __restrict__ c_dst,
    const unsigned short* __restrict__ Whi, const unsigned short* __restrict__ Wlo,
    const unsigned short* __restrict__ Wrhi, const unsigned short* __restrict__ Wrlo,
    const float* __restrict__ bias_h, const float* __restrict__ bias_r,
    float* __restrict__ yout,
    float* __restrict__ gsum, float* __restrict__ gsq) {
    __shared__ float Af[16 * 132];  // 8.4 KB: A tile (agg rows, f32)
    __shared__ float Y[16 * 132];   // 8.4 KB: y staging

    const int wave = threadIdx.x >> 6;
    const int lane = threadIdx.x & 63;
    const int quad = lane >> 4;
    const int l16 = lane & 15;

    // ---- preload this wave's 32-col weight frags into VGPRs (8 frags x 4 sets)
    short8 wHf[8], wLf[8], rHf[8], rLf[8];
#pragma unroll
    for (int f = 0; f < 8; f++) {
        int nt = wave * 2 + (f >> 2), ks = f & 3;
        int gi = (nt * 4 + ks) * 64 + lane;
        wHf[f] = __builtin_bit_cast(short8, ((const uint4*)Whi)[gi]);
        wLf[f] = __builtin_bit_cast(short8, ((const uint4*)Wlo)[gi]);
        rHf[f] = __builtin_bit_cast(short8, ((const uint4*)Wrhi)[gi]);
        rLf[f] = __builtin_bit_cast(short8, ((const uint4*)Wrlo)[gi]);
    }
    float bh[2], brr[2];
#pragma unroll
    for (int ntl = 0; ntl < 2; ntl++) {
        int col = wave * 32 + ntl * 16 + l16;
        bh[ntl] = bias_h[col];
        brr[ntl] = bias_r[col];
    }

    float s_acc[2] = {0.f, 0.f}, q_acc[2] = {0.f, 0.f};

    for (int rt = blockIdx.x; rt < NTILES; rt += gridDim.x) {
        const int rowbase = rt * 16;

        // ---- phase A: gather agg rows for this tile into LDS (wave w -> rows w*4..w*4+3)
#pragma unroll
        for (int i = 0; i < 4; i++) {
            const int r = wave * 4 + i;
            const int n = rowbase + r;
            const int beg = rowStart[n], end = rowStart[n + 1];
            float a0 = 0.f, a1 = 0.f;
            for (int j = beg; j < end; j++) {
                int s = esorted[j];
                float c = c_src[s];
                float2 pk = ((const float2*)(x + (size_t)s * D))[lane];
                a0 += pk.x * c;
                a1 += pk.y * c;
            }
            const float cd = c_dst[n];
            *(float2*)&Af[r * 132 + lane * 2] = float2{a0 * cd, a1 * cd};
        }
        __syncthreads();

        // ---- phase B: fragments. agg from LDS, x from global; split to bf16 hi/lo
        const int arow = rowbase + l16;
        short8 aH[4], aL[4], xH[4], xL[4];
        {
            float4 rx[8];
            const float4* xp = (const float4*)(x + (size_t)arow * D + quad * 8);
#pragma unroll
            for (int ks = 0; ks < 4; ks++) {
                rx[ks * 2] = xp[ks * 8];
                rx[ks * 2 + 1] = xp[ks * 8 + 1];
            }
#pragma unroll
            for (int ks = 0; ks < 4; ks++) {
                const float* ap = &Af[l16 * 132 + ks * 32 + quad * 8];
                float4 f0 = *(const float4*)ap;
                float4 f1 = *(const float4*)(ap + 4);
                float va[8] = {f0.x, f0.y, f0.z, f0.w, f1.x, f1.y, f1.z, f1.w};
                float vx[8] = {rx[ks * 2].x, rx[ks * 2].y, rx[ks * 2].z, rx[ks * 2].w,
                               rx[ks * 2 + 1].x, rx[ks * 2 + 1].y, rx[ks * 2 + 1].z, rx[ks * 2 + 1].w};
                short8 h1, l1, h2, l2;
#pragma unroll
                for (int j = 0; j < 8; j++) {
                    short hh, ll;
                    splitbf(va[j], hh, ll);
                    h1[j] = hh; l1[j] = ll;
                    splitbf(vx[j], hh, ll);
                    h2[j] = hh; l2[j] = ll;
                }
                aH[ks] = h1; aL[ks] = l1;
                xH[ks] = h2; xL[ks] = l2;
            }
        }

        // ---- MFMA: 2 ntiles x 4 ks x (3 split-terms x 2 matrices)
        f32x4 accH[2], accR[2];
#pragma unroll
        for (int ntl = 0; ntl < 2; ntl++) {
            accH[ntl] = f32x4{0.f, 0.f, 0.f, 0.f};
            accR[ntl] = f32x4{0.f, 0.f, 0.f, 0.f};
#pragma unroll
            for (int ks = 0; ks < 4; ks++) {
                const int f = ntl * 4 + ks;
                accH[ntl] = __builtin_amdgcn_mfma_f32_16x16x32_bf16(aH[ks], wHf[f], accH[ntl], 0, 0, 0);
                accH[ntl] = __builtin_amdgcn_mfma_f32_16x16x32_bf16(aH[ks], wLf[f], accH[ntl], 0, 0, 0);
                accH[ntl] = __builtin_amdgcn_mfma_f32_16x16x32_bf16(aL[ks], wHf[f], accH[ntl], 0, 0, 0);
                accR[ntl] = __builtin_amdgcn_mfma_f32_16x16x32_bf16(xH[ks], rHf[f], accR[ntl], 0, 0, 0);
                accR[ntl] = __builtin_amdgcn_mfma_f32_16x16x32_bf16(xH[ks], rLf[f], accR[ntl], 0, 0, 0);
                accR[ntl] = __builtin_amdgcn_mfma_f32_16x16x32_bf16(xL[ks], rHf[f], accR[ntl], 0, 0, 0);
            }
        }

        // ---- epilogue: y -> shared LDS tile + BN partials
#pragma unroll
        for (int ntl = 0; ntl < 2; ntl++) {
            float s = 0.f, q = 0.f;
#pragma unroll
            for (int r = 0; r < 4; r++) {
                float y = fmaxf(accH[ntl][r] + bh[ntl], 0.f) + fmaxf(accR[ntl][r] + brr[ntl], 0.f);
                Y[(quad * 4 + r) * 132 + wave * 32 + ntl * 16 + l16] = y;
                s += y;
                q += y * y;
            }
            s_acc[ntl] += s;
            q_acc[ntl] += q;
        }
        __syncthreads();
        // ---- store full 512B rows: 32 threads x float4 per row
#pragma unroll
        for (int j = 0; j < 2; j++) {
            int t = threadIdx.x + j * 256;
            int row = t >> 5, c4 = t & 31;
            float4 v = *(const float4*)&Y[row * 132 + c4 * 4];
            ((float4*)(yout + (size_t)(rowbase + row) * D))[c4] = v;
        }
        __syncthreads();
    }

    // ---- per-wave stats: quads hold same column set
#pragma unroll
    for (int ntl = 0; ntl < 2; ntl++) {
        float s = s_acc[ntl], q = q_acc[ntl];
        s += __shfl_xor(s, 16, 64);
        s += __shfl_xor(s, 32, 64);
        q += __shfl_xor(q, 16, 64);
        q += __shfl_xor(q, 32, 64);
        if (lane < 16) {
            unsafeAtomicAdd(&gsum[wave * 32 + ntl * 16 + lane], s);
            unsafeAtomicAdd(&gsq[wave * 32 + ntl * 16 + lane], q);
        }
    }
}

// ---------------------------------------------------------------- BN stats -> scale/shift (f32)
__global__ void k_bn_stats(const float* __restrict__ gsum, const float* __restrict__ gsq,
                           const float* __restrict__ gamma, const float* __restrict__ beta,
                           float* __restrict__ scale, float* __restrict__ shift) {
    int f = threadIdx.x;   // 128 threads
    const float invN = 1.0f / (float)N_NODES;
    float mean = gsum[f] * invN;
    float var = fmaxf(gsq[f] * invN - mean * mean, 0.f);
    float sc = gamma[f] * rsqrtf(var + BN_EPS);
    scale[f] = sc;
    shift[f] = beta[f] - mean * sc;
}

// ---------------------------------------------------------------- apply BN in-place on d_out (f32)
__global__ void k_bn_apply(float* __restrict__ y,
                           const float* __restrict__ scale, const float* __restrict__ shift) {
    int t = blockIdx.x * blockDim.x + threadIdx.x;
    const int total4 = N_NODES * D / 4;
    if (t >= total4) return;
    float4 v = ((float4*)y)[t];
    int f = (t * 4) & (D - 1);
    v.x = v.x * scale[f] + shift[f];
    v.y = v.y * scale[f + 1] + shift[f + 1];
    v.z = v.z * scale[f + 2] + shift[f + 2];
    v.w = v.w * scale[f + 3] + shift[f + 3];
    ((float4*)y)[t] = v;
}

// ---------------------------------------------------------------- launch
extern "C" void kernel_launch(void* const* d_in, const int* in_sizes, int n_in,
                              void* d_out, int out_size, void* d_ws, size_t ws_size,
                              hipStream_t stream) {
    const float* x     = (const float*)d_in[0];   // node_feats f32 [N,128]
    const float* W     = (const float*)d_in[1];
    const float* b     = (const float*)d_in[2];
    const float* Wr    = (const float*)d_in[3];
    const float* br    = (const float*)d_in[4];
    const float* gamma = (const float*)d_in[5];
    const float* beta  = (const float*)d_in[6];
    const int* src = (const int*)d_in[7];
    const int* dst = (const int*)d_in[8];
    float* out = (float*)d_out;

    const int NB1 = (N_NODES + 255) / 256;   // 391 scan blocks

    char* ws = (char*)d_ws;
    size_t off = 0;
    // ---- zeroed prefix (one contiguous memset, ~0.8 MB) ----
    float* gsum    = (float*)(ws + off); off += 512;
    float* gsq     = (float*)(ws + off); off += 512;
    int* cnt_src   = (int*)(ws + off); off += 400128;   // N*4 padded to 256
    int* cnt_dst   = (int*)(ws + off); off += 400128;
    const size_t zero_bytes = off;
    // ---- non-zeroed scratch ----
    int* fill      = (int*)(ws + off); off += 400128;   // zeroed by k_coeffs
    int* rowStart  = (int*)(ws + off); off += 400384;   // (N+1)*4 padded
    int* bsum      = (int*)(ws + off); off += 2048;     // NB1*4 padded
    int* esorted   = (int*)(ws + off); off += (size_t)N_EDGES * 4;   // 1.6 MB
    float* c_src   = (float*)(ws + off); off += 400128;
    float* c_dst   = (float*)(ws + off); off += 400128;
    unsigned short* WhiF  = (unsigned short*)(ws + off); off += 32768;
    unsigned short* WloF  = (unsigned short*)(ws + off); off += 32768;
    unsigned short* WrhiF = (unsigned short*)(ws + off); off += 32768;
    unsigned short* WrloF = (unsigned short*)(ws + off); off += 32768;
    float* scale = (float*)(ws + off); off += 512;
    float* shift = (float*)(ws + off); off += 512;
    const size_t needed = off;

    if (ws_size < needed) {
        k_zero_out<<<(N_NODES * D / 4 + 255) / 256, 256, 0, stream>>>(out, N_NODES * D / 4);
        return;
    }

    hipMemsetAsync(d_ws, 0, zero_bytes, stream);

    k_make_frags<<<16, 256, 0, stream>>>(W, Wr, WhiF, WloF, WrhiF, WrloF);
    // ---- counting sort of edges by dst ----
    k_count<<<(N_EDGES + 255) / 256, 256, 0, stream>>>(src, dst, cnt_src, cnt_dst);
    k_coeffs<<<NB1, 256, 0, stream>>>(cnt_src, cnt_dst, c_src, c_dst, fill);
    k_scan1<<<NB1, 256, 0, stream>>>(cnt_dst, rowStart, bsum);
    k_scan2<<<1, 512, 0, stream>>>(bsum, NB1);
    k_scan3<<<NB1, 256, 0, stream>>>(rowStart, bsum);
    k_fill<<<(N_EDGES + 255) / 256, 256, 0, stream>>>(src, dst, rowStart, fill, esorted);
    // ---- fused gather + dual GEMM + relu + add + BN partials ----
    k_gemm_fused<<<2048, 256, 0, stream>>>(x, esorted, rowStart, c_src, c_dst,
                                           WhiF, WloF, WrhiF, WrloF,
                                           b, br, out, gsum, gsq);
    k_bn_stats<<<1, 128, 0, stream>>>(gsum, gsq, gamma, beta, scale, shift);
    k_bn_apply<<<(N_NODES * D / 4 + 255) / 256, 256, 0, stream>>>(out, scale, shift);
}

// Round 10
// 404.164 us; speedup vs baseline: 1.1091x; 1.1091x over previous
//
#include <hip/hip_runtime.h>

#define N_NODES 100000
#define N_EDGES 400000
#define D 128
#define BN_EPS 1e-5f
#define NTILES 6250   // N_NODES/16

typedef short short8 __attribute__((ext_vector_type(8)));   // 8 bf16 as raw shorts (4 VGPRs)
typedef float f32x4 __attribute__((ext_vector_type(4)));

static __device__ __forceinline__ float bf2f(unsigned short u) {
    unsigned x = ((unsigned)u) << 16;
    return __builtin_bit_cast(float, x);
}
static __device__ __forceinline__ unsigned short f2bf(float f) {
    unsigned x = __builtin_bit_cast(unsigned, f);
    x += 0x7fffu + ((x >> 16) & 1u);   // round-to-nearest-even
    return (unsigned short)(x >> 16);
}
// split f32 into bf16 hi + bf16 lo (a ~= hi + lo, residual ~2^-17 rel)
static __device__ __forceinline__ void splitbf(float a, short& hi, short& lo) {
    unsigned short h = f2bf(a);
    float r = a - bf2f(h);
    hi = (short)h;
    lo = (short)f2bf(r);
}

// ---------------------------------------------------------------- fallback: clean zero-fill of d_out
__global__ void k_zero_out(float* __restrict__ y, int n4) {
    int t = blockIdx.x * blockDim.x + threadIdx.x;
    if (t < n4) ((float4*)y)[t] = float4{0.f, 0.f, 0.f, 0.f};
}

// ---------------------------------------------------------------- degree histograms
__global__ void k_count(const int* __restrict__ src, const int* __restrict__ dst,
                        int* __restrict__ cnt_src, int* __restrict__ cnt_dst) {
    int t = blockIdx.x * blockDim.x + threadIdx.x;
    if (t >= N_EDGES) return;
    atomicAdd(&cnt_src[src[t]], 1);
    atomicAdd(&cnt_dst[dst[t]], 1);
}

// ---------------------------------------------------------------- rsqrt coeffs (+ zero the fill cursors)
__global__ void k_coeffs(const int* __restrict__ cnt_src, const int* __restrict__ cnt_dst,
                         float* __restrict__ c_src, float* __restrict__ c_dst,
                         int* __restrict__ fill) {
    int t = blockIdx.x * blockDim.x + threadIdx.x;
    if (t >= N_NODES) return;
    c_src[t] = rsqrtf(fmaxf((float)cnt_src[t], 1.0f));
    c_dst[t] = rsqrtf(fmaxf((float)cnt_dst[t], 1.0f));
    fill[t] = 0;
}

// ---------------------------------------------------------------- exclusive scan, level 1 (256/block)
__global__ void k_scan1(const int* __restrict__ cnt, int* __restrict__ outp,
                        int* __restrict__ bsum) {
    __shared__ int s[256];
    int i = blockIdx.x * 256 + threadIdx.x;
    int v = (i < N_NODES) ? cnt[i] : 0;
    s[threadIdx.x] = v;
    __syncthreads();
    for (int d = 1; d < 256; d <<= 1) {
        int t = (threadIdx.x >= d) ? s[threadIdx.x - d] : 0;
        __syncthreads();
        s[threadIdx.x] += t;
        __syncthreads();
    }
    if (i < N_NODES) outp[i] = s[threadIdx.x] - v;   // exclusive
    if (threadIdx.x == 255) bsum[blockIdx.x] = s[255];
}

// ---------------------------------------------------------------- exclusive scan, level 2 (single block, nb<=512)
__global__ void k_scan2(int* __restrict__ bsum, int nb) {
    __shared__ int s[512];
    int v = (threadIdx.x < nb) ? bsum[threadIdx.x] : 0;
    s[threadIdx.x] = v;
    __syncthreads();
    for (int d = 1; d < 512; d <<= 1) {
        int t = (threadIdx.x >= d) ? s[threadIdx.x - d] : 0;
        __syncthreads();
        s[threadIdx.x] += t;
        __syncthreads();
    }
    if (threadIdx.x < nb) bsum[threadIdx.x] = s[threadIdx.x] - v;
}

// ---------------------------------------------------------------- scan fixup
__global__ void k_scan3(int* __restrict__ rowStart, const int* __restrict__ boff) {
    int i = blockIdx.x * 256 + threadIdx.x;
    if (i < N_NODES) rowStart[i] += boff[i >> 8];
    if (i == 0) rowStart[N_NODES] = N_EDGES;
}

// ---------------------------------------------------------------- bucket-fill: edge srcs sorted by dst
__global__ void k_fill(const int* __restrict__ src, const int* __restrict__ dst,
                       const int* __restrict__ rowStart, int* __restrict__ fill,
                       int* __restrict__ esorted) {
    int e = blockIdx.x * blockDim.x + threadIdx.x;
    if (e >= N_EDGES) return;
    int d = dst[e];
    int pos = rowStart[d] + atomicAdd(&fill[d], 1);
    esorted[pos] = src[e];
}

// ---------------------------------------------------------------- segmented gather: one wave per node
// aggS[n] = split-bf16 of c_dst[n] * sum c_src[s]*x[s] : 128 hi shorts then 128 lo shorts (512B/row)
// edge loop unrolled x2 with independent accumulators -> 2 row-loads in flight
__global__ void k_gather(const float* __restrict__ x,
                         const int* __restrict__ esorted, const int* __restrict__ rowStart,
                         const float* __restrict__ c_src, const float* __restrict__ c_dst,
                         unsigned short* __restrict__ aggS) {
    int n = blockIdx.x * 4 + (threadIdx.x >> 6);
    if (n >= N_NODES) return;
    int lane = threadIdx.x & 63;
    int beg = rowStart[n], end = rowStart[n + 1];
    float a0 = 0.f, a1 = 0.f, b0 = 0.f, b1 = 0.f;
    int j = beg;
    for (; j + 1 < end; j += 2) {
        int s0 = esorted[j], s1 = esorted[j + 1];
        float c0 = c_src[s0], c1 = c_src[s1];
        float2 p0 = ((const float2*)(x + (size_t)s0 * D))[lane];
        float2 p1 = ((const float2*)(x + (size_t)s1 * D))[lane];
        a0 += p0.x * c0;
        a1 += p0.y * c0;
        b0 += p1.x * c1;
        b1 += p1.y * c1;
    }
    if (j < end) {
        int s0 = esorted[j];
        float c0 = c_src[s0];
        float2 p0 = ((const float2*)(x + (size_t)s0 * D))[lane];
        a0 += p0.x * c0;
        a1 += p0.y * c0;
    }
    a0 += b0;
    a1 += b1;
    float cd = c_dst[n];
    a0 *= cd; a1 *= cd;
    short h0, l0, h1, l1;
    splitbf(a0, h0, l0);
    splitbf(a1, h1, l1);
    unsigned hi = (unsigned)(unsigned short)h0 | ((unsigned)(unsigned short)h1 << 16);
    unsigned lo = (unsigned)(unsigned short)l0 | ((unsigned)(unsigned short)l1 << 16);
    unsigned* base = (unsigned*)(aggS + (size_t)n * 256);
    base[lane] = hi;        // bytes [0,256): hi plane
    base[64 + lane] = lo;   // bytes [256,512): lo plane
}

// ---------------------------------------------------------------- W(f32) -> MFMA B-fragment order, split hi/lo bf16
// frag layout: fragIdx = ntile*4 + kstep; element j of lane l = W[kstep*32 + (l>>4)*8 + j][ntile*16 + (l&15)]
__global__ void k_make_frags(const float* __restrict__ W,
                             const float* __restrict__ Wr,
                             unsigned short* __restrict__ Whi, unsigned short* __restrict__ Wlo,
                             unsigned short* __restrict__ Wrhi, unsigned short* __restrict__ Wrlo) {
    int t = blockIdx.x * blockDim.x + threadIdx.x;   // 0..4095
    if (t >= 4096) return;
    int mat = t >> 11;
    int fragIdx = (t >> 6) & 31;
    int lane = t & 63;
    int nt = fragIdx >> 2, ks = fragIdx & 3;
    const float* Wsrc = mat ? Wr : W;
    unsigned short* dhi = mat ? Wrhi : Whi;
    unsigned short* dlo = mat ? Wrlo : Wlo;
    int n = nt * 16 + (lane & 15);
    int kbase = ks * 32 + (lane >> 4) * 8;
    short hi[8], lo[8];
#pragma unroll
    for (int j = 0; j < 8; j++) splitbf(Wsrc[(kbase + j) * D + n], hi[j], lo[j]);
    ((uint4*)dhi)[fragIdx * 64 + lane] = *(uint4*)hi;
    ((uint4*)dlo)[fragIdx * 64 + lane] = *(uint4*)lo;
}

// ---------------------------------------------------------------- merged dual GEMM, weights-in-VGPR
// block = 4 waves; wave w owns cols [w*32, w*32+32). All waves share each 16-row tile;
// y staged in one LDS tile, stored as full 512B rows. bf16x3 split precision.
__global__ __launch_bounds__(256, 4) void k_gemm_merged(
    const unsigned short* __restrict__ aggS,   // [N][256] shorts: hi|lo planes
    const float* __restrict__ x,               // [N,128] f32
    const unsigned short* __restrict__ Whi, const unsigned short* __restrict__ Wlo,
    const unsigned short* __restrict__ Wrhi, const unsigned short* __restrict__ Wrlo,
    const float* __restrict__ bias_h, const float* __restrict__ bias_r,
    float* __restrict__ yout,
    float* __restrict__ gsum, float* __restrict__ gsq) {
    __shared__ float Y[16 * 132];   // 8.4 KB, +4 pad breaks quad bank aliasing

    const int wave = threadIdx.x >> 6;
    const int lane = threadIdx.x & 63;
    const int quad = lane >> 4;
    const int l16 = lane & 15;

    // ---- preload this wave's 32-col weight frags into VGPRs (8 frags x 4 sets)
    short8 wHf[8], wLf[8], rHf[8], rLf[8];
#pragma unroll
    for (int f = 0; f < 8; f++) {
        int nt = wave * 2 + (f >> 2), ks = f & 3;
        int gi = (nt * 4 + ks) * 64 + lane;
        wHf[f] = __builtin_bit_cast(short8, ((const uint4*)Whi)[gi]);
        wLf[f] = __builtin_bit_cast(short8, ((const uint4*)Wlo)[gi]);
        rHf[f] = __builtin_bit_cast(short8, ((const uint4*)Wrhi)[gi]);
        rLf[f] = __builtin_bit_cast(short8, ((const uint4*)Wrlo)[gi]);
    }
    float bh[2], brr[2];
#pragma unroll
    for (int ntl = 0; ntl < 2; ntl++) {
        int col = wave * 32 + ntl * 16 + l16;
        bh[ntl] = bias_h[col];
        brr[ntl] = bias_r[col];
    }

    float s_acc[2] = {0.f, 0.f}, q_acc[2] = {0.f, 0.f};

    for (int rt = blockIdx.x; rt < NTILES; rt += gridDim.x) {
        const int rowbase = rt * 16;
        const int arow = rowbase + l16;

        // ---- agg frags: direct uint4 loads (pre-split by k_gather)
        short8 aH[4], aL[4];
        const uint4* agp = (const uint4*)(aggS + (size_t)arow * 256);
#pragma unroll
        for (int ks = 0; ks < 4; ks++) {
            aH[ks] = __builtin_bit_cast(short8, agp[ks * 4 + quad]);
            aL[ks] = __builtin_bit_cast(short8, agp[16 + ks * 4 + quad]);
        }
        // ---- x: load f32, split in-register
        float4 rx[8];
        const float4* xp = (const float4*)(x + (size_t)arow * D + quad * 8);
#pragma unroll
        for (int ks = 0; ks < 4; ks++) {
            rx[ks * 2] = xp[ks * 8];
            rx[ks * 2 + 1] = xp[ks * 8 + 1];
        }
        short8 xH[4], xL[4];
#pragma unroll
        for (int ks = 0; ks < 4; ks++) {
            float v[8] = {rx[ks * 2].x, rx[ks * 2].y, rx[ks * 2].z, rx[ks * 2].w,
                          rx[ks * 2 + 1].x, rx[ks * 2 + 1].y, rx[ks * 2 + 1].z, rx[ks * 2 + 1].w};
            short8 h, l;
#pragma unroll
            for (int j = 0; j < 8; j++) {
                short hh, ll;
                splitbf(v[j], hh, ll);
                h[j] = hh; l[j] = ll;
            }
            xH[ks] = h; xL[ks] = l;
        }

        // ---- MFMA: 2 ntiles x 4 ks x (3 split-terms x 2 matrices)
        f32x4 accH[2], accR[2];
#pragma unroll
        for (int ntl = 0; ntl < 2; ntl++) {
            accH[ntl] = f32x4{0.f, 0.f, 0.f, 0.f};
            accR[ntl] = f32x4{0.f, 0.f, 0.f, 0.f};
#pragma unroll
            for (int ks = 0; ks < 4; ks++) {
                const int f = ntl * 4 + ks;
                accH[ntl] = __builtin_amdgcn_mfma_f32_16x16x32_bf16(aH[ks], wHf[f], accH[ntl], 0, 0, 0);
                accH[ntl] = __builtin_amdgcn_mfma_f32_16x16x32_bf16(aH[ks], wLf[f], accH[ntl], 0, 0, 0);
                accH[ntl] = __builtin_amdgcn_mfma_f32_16x16x32_bf16(aL[ks], wHf[f], accH[ntl], 0, 0, 0);
                accR[ntl] = __builtin_amdgcn_mfma_f32_16x16x32_bf16(xH[ks], rHf[f], accR[ntl], 0, 0, 0);
                accR[ntl] = __builtin_amdgcn_mfma_f32_16x16x32_bf16(xH[ks], rLf[f], accR[ntl], 0, 0, 0);
                accR[ntl] = __builtin_amdgcn_mfma_f32_16x16x32_bf16(xL[ks], rHf[f], accR[ntl], 0, 0, 0);
            }
        }

        // ---- epilogue: y -> shared LDS tile + BN partials
#pragma unroll
        for (int ntl = 0; ntl < 2; ntl++) {
            float s = 0.f, q = 0.f;
#pragma unroll
            for (int r = 0; r < 4; r++) {
                float y = fmaxf(accH[ntl][r] + bh[ntl], 0.f) + fmaxf(accR[ntl][r] + brr[ntl], 0.f);
                Y[(quad * 4 + r) * 132 + wave * 32 + ntl * 16 + l16] = y;
                s += y;
                q += y * y;
            }
            s_acc[ntl] += s;
            q_acc[ntl] += q;
        }
        __syncthreads();
        // ---- store full 512B rows: 32 threads x float4 per row
#pragma unroll
        for (int j = 0; j < 2; j++) {
            int t = threadIdx.x + j * 256;
            int row = t >> 5, c4 = t & 31;
            float4 v = *(const float4*)&Y[row * 132 + c4 * 4];
            ((float4*)(yout + (size_t)(rowbase + row) * D))[c4] = v;
        }
        __syncthreads();
    }

    // ---- per-wave stats: quads hold same column set
#pragma unroll
    for (int ntl = 0; ntl < 2; ntl++) {
        float s = s_acc[ntl], q = q_acc[ntl];
        s += __shfl_xor(s, 16, 64);
        s += __shfl_xor(s, 32, 64);
        q += __shfl_xor(q, 16, 64);
        q += __shfl_xor(q, 32, 64);
        if (lane < 16) {
            unsafeAtomicAdd(&gsum[wave * 32 + ntl * 16 + lane], s);
            unsafeAtomicAdd(&gsq[wave * 32 + ntl * 16 + lane], q);
        }
    }
}

// ---------------------------------------------------------------- BN stats -> scale/shift (f32)
__global__ void k_bn_stats(const float* __restrict__ gsum, const float* __restrict__ gsq,
                           const float* __restrict__ gamma, const float* __restrict__ beta,
                           float* __restrict__ scale, float* __restrict__ shift) {
    int f = threadIdx.x;   // 128 threads
    const float invN = 1.0f / (float)N_NODES;
    float mean = gsum[f] * invN;
    float var = fmaxf(gsq[f] * invN - mean * mean, 0.f);
    float sc = gamma[f] * rsqrtf(var + BN_EPS);
    scale[f] = sc;
    shift[f] = beta[f] - mean * sc;
}

// ---------------------------------------------------------------- apply BN in-place on d_out (f32)
__global__ void k_bn_apply(float* __restrict__ y,
                           const float* __restrict__ scale, const float* __restrict__ shift) {
    int t = blockIdx.x * blockDim.x + threadIdx.x;
    const int total4 = N_NODES * D / 4;
    if (t >= total4) return;
    float4 v = ((float4*)y)[t];
    int f = (t * 4) & (D - 1);
    v.x = v.x * scale[f] + shift[f];
    v.y = v.y * scale[f + 1] + shift[f + 1];
    v.z = v.z * scale[f + 2] + shift[f + 2];
    v.w = v.w * scale[f + 3] + shift[f + 3];
    ((float4*)y)[t] = v;
}

// ---------------------------------------------------------------- launch
extern "C" void kernel_launch(void* const* d_in, const int* in_sizes, int n_in,
                              void* d_out, int out_size, void* d_ws, size_t ws_size,
                              hipStream_t stream) {
    const float* x     = (const float*)d_in[0];   // node_feats f32 [N,128]
    const float* W     = (const float*)d_in[1];
    const float* b     = (const float*)d_in[2];
    const float* Wr    = (const float*)d_in[3];
    const float* br    = (const float*)d_in[4];
    const float* gamma = (const float*)d_in[5];
    const float* beta  = (const float*)d_in[6];
    const int* src = (const int*)d_in[7];
    const int* dst = (const int*)d_in[8];
    float* out = (float*)d_out;

    const int NB1 = (N_NODES + 255) / 256;   // 391 scan blocks

    char* ws = (char*)d_ws;
    size_t off = 0;
    // ---- zeroed prefix (one contiguous memset, ~0.8 MB) ----
    float* gsum    = (float*)(ws + off); off += 512;
    float* gsq     = (float*)(ws + off); off += 512;
    int* cnt_src   = (int*)(ws + off); off += 400128;   // N*4 padded to 256
    int* cnt_dst   = (int*)(ws + off); off += 400128;
    const size_t zero_bytes = off;
    // ---- non-zeroed scratch ----
    int* fill      = (int*)(ws + off); off += 400128;   // zeroed by k_coeffs
    int* rowStart  = (int*)(ws + off); off += 400384;   // (N+1)*4 padded
    int* bsum      = (int*)(ws + off); off += 2048;     // NB1*4 padded
    int* esorted   = (int*)(ws + off); off += (size_t)N_EDGES * 4;   // 1.6 MB
    unsigned short* aggS = (unsigned short*)(ws + off); off += (size_t)N_NODES * 512;  // 51.2 MB
    float* c_src   = (float*)(ws + off); off += 400128;
    float* c_dst   = (float*)(ws + off); off += 400128;
    unsigned short* WhiF  = (unsigned short*)(ws + off); off += 32768;
    unsigned short* WloF  = (unsigned short*)(ws + off); off += 32768;
    unsigned short* WrhiF = (unsigned short*)(ws + off); off += 32768;
    unsigned short* WrloF = (unsigned short*)(ws + off); off += 32768;
    float* scale = (float*)(ws + off); off += 512;
    float* shift = (float*)(ws + off); off += 512;
    const size_t needed = off;

    if (ws_size < needed) {
        k_zero_out<<<(N_NODES * D / 4 + 255) / 256, 256, 0, stream>>>(out, N_NODES * D / 4);
        return;
    }

    hipMemsetAsync(d_ws, 0, zero_bytes, stream);

    k_make_frags<<<16, 256, 0, stream>>>(W, Wr, WhiF, WloF, WrhiF, WrloF);
    // ---- counting sort of edges by dst ----
    k_count<<<(N_EDGES + 255) / 256, 256, 0, stream>>>(src, dst, cnt_src, cnt_dst);
    k_coeffs<<<NB1, 256, 0, stream>>>(cnt_src, cnt_dst, c_src, c_dst, fill);
    k_scan1<<<NB1, 256, 0, stream>>>(cnt_dst, rowStart, bsum);
    k_scan2<<<1, 512, 0, stream>>>(bsum, NB1);
    k_scan3<<<NB1, 256, 0, stream>>>(rowStart, bsum);
    k_fill<<<(N_EDGES + 255) / 256, 256, 0, stream>>>(src, dst, rowStart, fill, esorted);
    // ---- segmented gather (c_dst folded in, emits split bf16 hi|lo) ----
    k_gather<<<(N_NODES + 3) / 4, 256, 0, stream>>>(x, esorted, rowStart, c_src, c_dst, aggS);
    // ---- merged dual GEMM + relu + add + BN partials ----
    k_gemm_merged<<<2048, 256, 0, stream>>>(aggS, x, WhiF, WloF, WrhiF, WrloF,
                                            b, br, out, gsum, gsq);
    k_bn_stats<<<1, 128, 0, stream>>>(gsum, gsq, gamma, beta, scale, shift);
    k_bn_apply<<<(N_NODES * D / 4 + 255) / 256, 256, 0, stream>>>(out, scale, shift);
}